// Round 9
// baseline (733.754 us; speedup 1.0000x reference)
//
#include <hip/hip_runtime.h>
#include <hip/hip_bf16.h>

typedef __attribute__((ext_vector_type(2))) float f32x2;
typedef __attribute__((ext_vector_type(8))) unsigned short ushort8;
typedef __attribute__((ext_vector_type(4))) unsigned short ushort4_t;

#define N_    4096
#define NSPL1 8   // lnattn splits  (4 blocks/CU)
#define NSPL2 4   // attnstep splits (2 blocks/CU)

__device__ inline float bf2f(unsigned short u){
  union{unsigned int i; float f;} c; c.i = ((unsigned int)u)<<16; return c.f;
}
__device__ inline unsigned short f2bf(float f){
  union{float f; unsigned int i;} c; c.f = f;
  unsigned int x = c.i;
  return (unsigned short)((x + 0x7fffu + ((x>>16)&1u)) >> 16);
}
__device__ inline float sigm(float s){ return 1.0f/(1.0f+__expf(-s)); }
__device__ inline f32x2 up2(unsigned int w){
  union{unsigned int i; float f;} lo, hi;
  lo.i = w<<16; hi.i = w & 0xffff0000u;
  f32x2 r; r.x = lo.f; r.y = hi.f; return r;
}

// 32-lane group sum via DPP row_ror (VALU pipe) + one cross-16 shuffle.
__device__ inline float rsum32(float v){
  union{float f; int i;} a, t;
  a.f = v;
  t.i = __builtin_amdgcn_update_dpp(0, a.i, 0x121, 0xF, 0xF, true); a.f += t.f;
  t.i = __builtin_amdgcn_update_dpp(0, a.i, 0x122, 0xF, 0xF, true); a.f += t.f;
  t.i = __builtin_amdgcn_update_dpp(0, a.i, 0x124, 0xF, 0xF, true); a.f += t.f;
  t.i = __builtin_amdgcn_update_dpp(0, a.i, 0x128, 0xF, 0xF, true); a.f += t.f;
  a.f += __shfl_xor(a.f, 16);
  return a.f;
}

// block = 256 threads (4 waves). Full block sum.
__device__ inline float blkSum(float v, float* s4){
  v += __shfl_xor(v,1);  v += __shfl_xor(v,2);  v += __shfl_xor(v,4);
  v += __shfl_xor(v,8);  v += __shfl_xor(v,16); v += __shfl_xor(v,32);
  int lane = threadIdx.x & 63, w = threadIdx.x >> 6;
  __syncthreads();
  if (lane==0) s4[w] = v;
  __syncthreads();
  return s4[0]+s4[1]+s4[2]+s4[3];
}

// block = 1024 threads (16 waves). Full block sum.
__device__ inline float blkSum16(float v, float* s16){
  #pragma unroll
  for(int o=1;o<64;o<<=1) v += __shfl_xor(v,o);
  int lane = threadIdx.x & 63, w = threadIdx.x >> 6;
  __syncthreads();
  if (lane==0) s16[w] = v;
  __syncthreads();
  float r = 0.f;
  #pragma unroll
  for(int i=0;i<16;i++) r += s16[i];
  return r;
}

// ---------------- prep: packed-k bf16 weights -----------------------------
__global__ __launch_bounds__(256) void k_prep(
    const float* __restrict__ Wv, const float* __restrict__ Wih,
    const float* __restrict__ Whh, const float* __restrict__ W1,
    const float* __restrict__ W2, const float* __restrict__ Wq,
    const float* __restrict__ Wk,
    unsigned short* __restrict__ Wvp, unsigned short* __restrict__ Wip,
    unsigned short* __restrict__ Whp, unsigned short* __restrict__ W1p,
    unsigned short* __restrict__ W2p, unsigned short* __restrict__ Wqp,
    unsigned short* __restrict__ Wkp){
  int e = blockIdx.x*256 + threadIdx.x;          // 0 .. 262143
  if (e < 65536){
    int i = e&3, j = (e>>2)&255, pk = e>>10;
    Wvp[e] = f2bf(Wv[(4*pk+i)*256 + j]);
    Wqp[e] = f2bf(Wq[(4*pk+i)*256 + j]);
  }
  if (e < 196608){
    int i = e&3, j2 = e>>2;
    int j = j2 % 768, pk = j2 / 768;
    Wip[e] = f2bf(Wih[j*256 + 4*pk+i]);
    Whp[e] = f2bf(Whh[j*256 + 4*pk+i]);
  }
  {
    int i = e&3, j = (e>>2)&1023, pk = e>>12;
    W1p[e] = f2bf(W1[(4*pk+i)*1024 + j]);
  }
  {
    int i = e&3, j = (e>>2)&255, pk = e>>10;
    W2p[e] = f2bf(W2[(4*pk+i)*256 + j]);
  }
  if (e < 65536){
    int i = e&3, hc = (e>>2)&1023, pd = e>>12;
    int h = hc>>8, c = hc&255;
    Wkp[e] = f2bf(Wk[c*256 + h*64 + 4*pd+i]);
  }
}

// ---------------- init: rep0 = mu + exp(.5 lv)*eps ; q0 -> p0 -------------
__global__ __launch_bounds__(256) void k_init(
    const float* __restrict__ eps, const float* __restrict__ mu0,
    const float* __restrict__ lv0, const float* __restrict__ sg,
    const float* __restrict__ sb, const float* __restrict__ Wq,
    const unsigned short* __restrict__ Wkp,
    float* __restrict__ rep, float* __restrict__ p_out){
  __shared__ float s4[4]; __shared__ float xq[256]; __shared__ float q_s[256];
  int b = blockIdx.x, c = threadIdx.x;
  float r0 = mu0[c] + __expf(0.5f*lv0[c]) * eps[b*256+c];
  rep[b*256+c] = r0;
  float mu = blkSum(r0, s4) * (1.0f/256.0f);
  float df = r0 - mu;
  float var = blkSum(df*df, s4) * (1.0f/256.0f);
  float rs = rsqrtf(var + 1e-5f);
  xq[c] = df*rs*sg[c] + sb[c];
  __syncthreads();
  float a0=0,a1=0,a2=0,a3=0;
  for(int k=0;k<256;k+=4){
    a0 += xq[k  ]*Wq[(k  )*256+c];
    a1 += xq[k+1]*Wq[(k+1)*256+c];
    a2 += xq[k+2]*Wq[(k+2)*256+c];
    a3 += xq[k+3]*Wq[(k+3)*256+c];
  }
  q_s[c] = a0+a1+a2+a3;
  __syncthreads();
  #pragma unroll
  for(int h=0;h<4;h++){
    float acc = 0.f;
    for(int pd=0;pd<16;pd++){
      ushort4_t w4 = *reinterpret_cast<const ushort4_t*>(Wkp + ((size_t)pd*1024 + h*256 + c)*4);
      acc += bf2f(w4.x)*q_s[h*64+4*pd  ] + bf2f(w4.y)*q_s[h*64+4*pd+1]
           + bf2f(w4.z)*q_s[h*64+4*pd+2] + bf2f(w4.w)*q_s[h*64+4*pd+3];
    }
    p_out[b*1024 + h*256 + c] = 2.0f*acc;
  }
}

// ---------------- fused input-LN + attention pass 1 -----------------------
// grid (NSPL1,128) x 1024 thr. 32 lanes/row, unroll-2 rows; DPP reductions.
__global__ __launch_bounds__(1024) void k_lnattn(
    const float* __restrict__ in, const float* __restrict__ g,
    const float* __restrict__ bln, const float* __restrict__ p,
    unsigned short* __restrict__ x,
    float* __restrict__ u_part, float* __restrict__ ws_part){
  __shared__ float u_red[8][1024];
  __shared__ float ws_red[16][4];
  int split = blockIdx.x, b = blockIdx.y;
  int tid = threadIdx.x, wid = tid>>6, lane = tid&63;
  int grp = tid>>5, cl = tid&31;
  const int ROWS = N_ / NSPL1;            // 512
  const float* pb = p + (size_t)b*1024;
  f32x2 pp2[4][4];
  #pragma unroll
  for(int h=0;h<4;h++){
    float4 pa = *reinterpret_cast<const float4*>(pb + h*256 + cl*8);
    float4 pc = *reinterpret_cast<const float4*>(pb + h*256 + cl*8 + 4);
    pp2[h][0] = f32x2{pa.x,pa.y}; pp2[h][1] = f32x2{pa.z,pa.w};
    pp2[h][2] = f32x2{pc.x,pc.y}; pp2[h][3] = f32x2{pc.z,pc.w};
  }
  float gg[8], bb[8];
  {
    float4 a = *reinterpret_cast<const float4*>(g + cl*8);
    float4 c = *reinterpret_cast<const float4*>(g + cl*8 + 4);
    gg[0]=a.x; gg[1]=a.y; gg[2]=a.z; gg[3]=a.w; gg[4]=c.x; gg[5]=c.y; gg[6]=c.z; gg[7]=c.w;
    a = *reinterpret_cast<const float4*>(bln + cl*8);
    c = *reinterpret_cast<const float4*>(bln + cl*8 + 4);
    bb[0]=a.x; bb[1]=a.y; bb[2]=a.z; bb[3]=a.w; bb[4]=c.x; bb[5]=c.y; bb[6]=c.z; bb[7]=c.w;
  }
  f32x2 u[4][4] = {};
  float wsum[4] = {0,0,0,0};
  const float* inb = in + ((size_t)b*N_ + split*ROWS)*256;
  unsigned short* xb = x + ((size_t)b*N_ + split*ROWS)*256;
  for(int it=0; it<ROWS/64; ++it){
    int r0 = it*64 + grp, r1 = r0 + 32;
    float4 a0 = *reinterpret_cast<const float4*>(inb + (size_t)r0*256 + cl*8);
    float4 c0 = *reinterpret_cast<const float4*>(inb + (size_t)r0*256 + cl*8 + 4);
    float4 a1 = *reinterpret_cast<const float4*>(inb + (size_t)r1*256 + cl*8);
    float4 c1 = *reinterpret_cast<const float4*>(inb + (size_t)r1*256 + cl*8 + 4);
    float sm0 = a0.x+a0.y+a0.z+a0.w + c0.x+c0.y+c0.z+c0.w;
    float sq0 = a0.x*a0.x+a0.y*a0.y+a0.z*a0.z+a0.w*a0.w
              + c0.x*c0.x+c0.y*c0.y+c0.z*c0.z+c0.w*c0.w;
    float sm1 = a1.x+a1.y+a1.z+a1.w + c1.x+c1.y+c1.z+c1.w;
    float sq1 = a1.x*a1.x+a1.y*a1.y+a1.z*a1.z+a1.w*a1.w
              + c1.x*c1.x+c1.y*c1.y+c1.z*c1.z+c1.w*c1.w;
    sm0 = rsum32(sm0); sq0 = rsum32(sq0);
    sm1 = rsum32(sm1); sq1 = rsum32(sq1);
    float mu0 = sm0*(1.0f/256.0f);
    float rs0 = rsqrtf(sq0*(1.0f/256.0f) - mu0*mu0 + 1e-5f);
    float mu1 = sm1*(1.0f/256.0f);
    float rs1 = rsqrtf(sq1*(1.0f/256.0f) - mu1*mu1 + 1e-5f);
    f32x2 px0[4], px1[4];
    px0[0].x=(a0.x-mu0)*rs0*gg[0]+bb[0]; px0[0].y=(a0.y-mu0)*rs0*gg[1]+bb[1];
    px0[1].x=(a0.z-mu0)*rs0*gg[2]+bb[2]; px0[1].y=(a0.w-mu0)*rs0*gg[3]+bb[3];
    px0[2].x=(c0.x-mu0)*rs0*gg[4]+bb[4]; px0[2].y=(c0.y-mu0)*rs0*gg[5]+bb[5];
    px0[3].x=(c0.z-mu0)*rs0*gg[6]+bb[6]; px0[3].y=(c0.w-mu0)*rs0*gg[7]+bb[7];
    px1[0].x=(a1.x-mu1)*rs1*gg[0]+bb[0]; px1[0].y=(a1.y-mu1)*rs1*gg[1]+bb[1];
    px1[1].x=(a1.z-mu1)*rs1*gg[2]+bb[2]; px1[1].y=(a1.w-mu1)*rs1*gg[3]+bb[3];
    px1[2].x=(c1.x-mu1)*rs1*gg[4]+bb[4]; px1[2].y=(c1.y-mu1)*rs1*gg[5]+bb[5];
    px1[3].x=(c1.z-mu1)*rs1*gg[6]+bb[6]; px1[3].y=(c1.w-mu1)*rs1*gg[7]+bb[7];
    ushort8 o8;
    o8[0]=f2bf(px0[0].x); o8[1]=f2bf(px0[0].y); o8[2]=f2bf(px0[1].x); o8[3]=f2bf(px0[1].y);
    o8[4]=f2bf(px0[2].x); o8[5]=f2bf(px0[2].y); o8[6]=f2bf(px0[3].x); o8[7]=f2bf(px0[3].y);
    *reinterpret_cast<ushort8*>(xb + (size_t)r0*256 + cl*8) = o8;
    o8[0]=f2bf(px1[0].x); o8[1]=f2bf(px1[0].y); o8[2]=f2bf(px1[1].x); o8[3]=f2bf(px1[1].y);
    o8[4]=f2bf(px1[2].x); o8[5]=f2bf(px1[2].y); o8[6]=f2bf(px1[3].x); o8[7]=f2bf(px1[3].y);
    *reinterpret_cast<ushort8*>(xb + (size_t)r1*256 + cl*8) = o8;
    float w0[4], w1[4];
    #pragma unroll
    for(int h=0;h<4;h++){
      f32x2 da = px0[0]*pp2[h][0] + px0[2]*pp2[h][2];
      f32x2 db = px0[1]*pp2[h][1] + px0[3]*pp2[h][3];
      da += db;
      float d0 = da.x + da.y;
      f32x2 ea = px1[0]*pp2[h][0] + px1[2]*pp2[h][2];
      f32x2 eb = px1[1]*pp2[h][1] + px1[3]*pp2[h][3];
      ea += eb;
      float d1 = ea.x + ea.y;
      d0 = rsum32(d0);
      d1 = rsum32(d1);
      w0[h] = sigm(d0) + 1e-8f;
      w1[h] = sigm(d1) + 1e-8f;
      wsum[h] += w0[h] + w1[h];
    }
    #pragma unroll
    for(int h=0;h<4;h++){
      f32x2 wa; wa.x = w0[h]; wa.y = w0[h];
      f32x2 wb; wb.x = w1[h]; wb.y = w1[h];
      #pragma unroll
      for(int j=0;j<4;j++){ u[h][j] += wa*px0[j]; u[h][j] += wb*px1[j]; }
    }
  }
  #pragma unroll
  for(int h=0;h<4;h++){
    #pragma unroll
    for(int j=0;j<4;j++){
      u[h][j].x += __shfl_xor(u[h][j].x,32);
      u[h][j].y += __shfl_xor(u[h][j].y,32);
    }
    wsum[h] += __shfl_xor(wsum[h],32);
  }
  if (wid < 8 && lane < 32){
    #pragma unroll
    for(int h=0;h<4;h++){
      float4 a; a.x=u[h][0].x; a.y=u[h][0].y; a.z=u[h][1].x; a.w=u[h][1].y;
      float4 c; c.x=u[h][2].x; c.y=u[h][2].y; c.z=u[h][3].x; c.w=u[h][3].y;
      *reinterpret_cast<float4*>(&u_red[wid][h*256 + cl*8    ]) = a;
      *reinterpret_cast<float4*>(&u_red[wid][h*256 + cl*8 + 4]) = c;
    }
  }
  if (lane==0){
    #pragma unroll
    for(int h=0;h<4;h++) ws_red[wid][h] = wsum[h];
  }
  __syncthreads();
  if (wid >= 8 && lane < 32){
    #pragma unroll
    for(int h=0;h<4;h++){
      float4 a = *reinterpret_cast<const float4*>(&u_red[wid-8][h*256 + cl*8]);
      float4 c = *reinterpret_cast<const float4*>(&u_red[wid-8][h*256 + cl*8 + 4]);
      a.x+=u[h][0].x; a.y+=u[h][0].y; a.z+=u[h][1].x; a.w+=u[h][1].y;
      c.x+=u[h][2].x; c.y+=u[h][2].y; c.z+=u[h][3].x; c.w+=u[h][3].y;
      *reinterpret_cast<float4*>(&u_red[wid-8][h*256 + cl*8    ]) = a;
      *reinterpret_cast<float4*>(&u_red[wid-8][h*256 + cl*8 + 4]) = c;
    }
  }
  __syncthreads();
  {
    float s = 0.f;
    #pragma unroll
    for(int w=0;w<8;w++) s += u_red[w][tid];
    u_part[((size_t)split*128 + b)*1024 + tid] = s;
  }
  if (tid < 4){
    float s = 0.f;
    #pragma unroll
    for(int w=0;w<16;w++) s += ws_red[w][tid];
    ws_part[((size_t)split*128 + b)*4 + tid] = s;
  }
}

// ---------------- fused step + attention pass -----------------------------
// grid (NSPL2,128) x 1024 thr; nsp_in = #partials to sum from previous pass.
__global__ __launch_bounds__(1024) void k_attnstep(
    const unsigned short* __restrict__ x,
    const float* __restrict__ u_in, const float* __restrict__ ws_in,
    const float* __restrict__ rep_in, float* __restrict__ rep_out,
    const unsigned short* __restrict__ Wvp, const unsigned short* __restrict__ Wip,
    const unsigned short* __restrict__ Whp, const float* __restrict__ bih,
    const float* __restrict__ bhh, const float* __restrict__ ln_rg,
    const float* __restrict__ ln_rb, const unsigned short* __restrict__ W1p,
    const unsigned short* __restrict__ W2p, const float* __restrict__ b2,
    const float* __restrict__ ln_sg, const float* __restrict__ ln_sb,
    const unsigned short* __restrict__ Wqp, const unsigned short* __restrict__ Wkp,
    float* __restrict__ u_out, float* __restrict__ ws_out,
    float* __restrict__ w_buf, int write_w, int nsp_in){
  __shared__ float u_s[1024];
  __shared__ float att_s[256], rep_s[256], ln_s[256], nw_s[256], q_s[256];
  __shared__ float gi_s[768], gh_s[768];
  __shared__ float h1_s[1024], p_s[1024], red_a[1024];
  __shared__ float ws_s[4]; __shared__ float s16[16];
  __shared__ float u_red[8][1024];
  __shared__ float ws_red[16][4];
  int split = blockIdx.x, b = blockIdx.y;
  int tid = threadIdx.x;
  int c = tid & 255, s = tid >> 8;
  const int ROWS = N_ / NSPL2;            // 1024
  // ---- phase S ----
  {
    float acc = 0.f;
    for(int sp=0; sp<nsp_in; ++sp)
      acc += u_in[((size_t)sp*128 + b)*1024 + tid];
    u_s[tid] = acc;
    if (tid < 4){
      float w = 0.f;
      for(int sp=0; sp<nsp_in; ++sp) w += ws_in[((size_t)sp*128 + b)*4 + tid];
      ws_s[tid] = w;
    }
    if (tid < 256) rep_s[tid] = rep_in[b*256 + tid];
  }
  __syncthreads();
  { // att partial
    const float* uh = u_s + (c>>6)*256;
    float a0 = 0.f, a1 = 0.f;
    for(int pk=s*16; pk<s*16+16; pk+=2){
      ushort4_t wa = *reinterpret_cast<const ushort4_t*>(Wvp + ((size_t)pk*256 + c)*4);
      ushort4_t wb = *reinterpret_cast<const ushort4_t*>(Wvp + ((size_t)(pk+1)*256 + c)*4);
      a0 += bf2f(wa.x)*uh[4*pk] + bf2f(wa.y)*uh[4*pk+1]
          + bf2f(wa.z)*uh[4*pk+2] + bf2f(wa.w)*uh[4*pk+3];
      a1 += bf2f(wb.x)*uh[4*pk+4] + bf2f(wb.y)*uh[4*pk+5]
          + bf2f(wb.z)*uh[4*pk+6] + bf2f(wb.w)*uh[4*pk+7];
    }
    red_a[tid] = a0+a1;
  }
  __syncthreads();
  if (tid < 256) att_s[tid] = (red_a[tid]+red_a[256+tid]+red_a[512+tid]+red_a[768+tid]) / ws_s[tid>>6];
  __syncthreads();
  if (tid < 768){ // GRU rows
    float gi0=0.f, gi1=0.f, gh0=0.f, gh1=0.f;
    for(int pk=0;pk<64;pk+=2){
      ushort4_t wi0 = *reinterpret_cast<const ushort4_t*>(Wip + ((size_t)pk*768 + tid)*4);
      ushort4_t wh0 = *reinterpret_cast<const ushort4_t*>(Whp + ((size_t)pk*768 + tid)*4);
      ushort4_t wi1 = *reinterpret_cast<const ushort4_t*>(Wip + ((size_t)(pk+1)*768 + tid)*4);
      ushort4_t wh1 = *reinterpret_cast<const ushort4_t*>(Whp + ((size_t)(pk+1)*768 + tid)*4);
      gi0 += bf2f(wi0.x)*att_s[4*pk] + bf2f(wi0.y)*att_s[4*pk+1]
           + bf2f(wi0.z)*att_s[4*pk+2] + bf2f(wi0.w)*att_s[4*pk+3];
      gh0 += bf2f(wh0.x)*rep_s[4*pk] + bf2f(wh0.y)*rep_s[4*pk+1]
           + bf2f(wh0.z)*rep_s[4*pk+2] + bf2f(wh0.w)*rep_s[4*pk+3];
      gi1 += bf2f(wi1.x)*att_s[4*pk+4] + bf2f(wi1.y)*att_s[4*pk+5]
           + bf2f(wi1.z)*att_s[4*pk+6] + bf2f(wi1.w)*att_s[4*pk+7];
      gh1 += bf2f(wh1.x)*rep_s[4*pk+4] + bf2f(wh1.y)*rep_s[4*pk+5]
           + bf2f(wh1.z)*rep_s[4*pk+6] + bf2f(wh1.w)*rep_s[4*pk+7];
    }
    gi_s[tid] = gi0+gi1 + bih[tid];
    gh_s[tid] = gh0+gh1 + bhh[tid];
  }
  __syncthreads();
  if (tid < 256){
    float rr = sigm(gi_s[tid]     + gh_s[tid]);
    float zz = sigm(gi_s[256+tid] + gh_s[256+tid]);
    float t3 = tanhf(gi_s[512+tid] + rr*gh_s[512+tid]);
    nw_s[tid] = (1.f-zz)*t3 + zz*rep_s[tid];
  }
  __syncthreads();
  { // residual LN
    float v = nw_s[c];
    float mu = blkSum16(v, s16)*(1.0f/1024.0f);
    float df = v - mu;
    float var = blkSum16(df*df, s16)*(1.0f/1024.0f);
    float rs = rsqrtf(var+1e-5f);
    if (s==0) ln_s[c] = df*rs*ln_rg[c]+ln_rb[c];
  }
  __syncthreads();
  { // W1
    float a0 = 0.f, a1 = 0.f;
    for(int pk=0;pk<64;pk+=2){
      ushort4_t wa = *reinterpret_cast<const ushort4_t*>(W1p + ((size_t)pk*1024 + tid)*4);
      ushort4_t wb = *reinterpret_cast<const ushort4_t*>(W1p + ((size_t)(pk+1)*1024 + tid)*4);
      a0 += bf2f(wa.x)*ln_s[4*pk] + bf2f(wa.y)*ln_s[4*pk+1]
          + bf2f(wa.z)*ln_s[4*pk+2] + bf2f(wa.w)*ln_s[4*pk+3];
      a1 += bf2f(wb.x)*ln_s[4*pk+4] + bf2f(wb.y)*ln_s[4*pk+5]
          + bf2f(wb.z)*ln_s[4*pk+6] + bf2f(wb.w)*ln_s[4*pk+7];
    }
    h1_s[tid] = fmaxf(a0+a1, 0.f);
  }
  __syncthreads();
  { // W2
    float a0 = 0.f, a1 = 0.f;
    for(int pk=s*64; pk<s*64+64; pk+=2){
      ushort4_t wa = *reinterpret_cast<const ushort4_t*>(W2p + ((size_t)pk*256 + c)*4);
      ushort4_t wb = *reinterpret_cast<const ushort4_t*>(W2p + ((size_t)(pk+1)*256 + c)*4);
      a0 += bf2f(wa.x)*h1_s[4*pk] + bf2f(wa.y)*h1_s[4*pk+1]
          + bf2f(wa.z)*h1_s[4*pk+2] + bf2f(wa.w)*h1_s[4*pk+3];
      a1 += bf2f(wb.x)*h1_s[4*pk+4] + bf2f(wb.y)*h1_s[4*pk+5]
          + bf2f(wb.z)*h1_s[4*pk+6] + bf2f(wb.w)*h1_s[4*pk+7];
    }
    red_a[tid] = a0+a1;
  }
  __syncthreads();
  if (tid < 256){
    float rn = nw_s[tid] + (red_a[tid]+red_a[256+tid]+red_a[512+tid]+red_a[768+tid]) + b2[tid];
    nw_s[tid] = rn;
    if (split==0) rep_out[b*256+tid] = rn;
  }
  __syncthreads();
  { // slot LN
    float v = nw_s[c];
    float mu = blkSum16(v, s16)*(1.0f/1024.0f);
    float df = v - mu;
    float var = blkSum16(df*df, s16)*(1.0f/1024.0f);
    float rs = rsqrtf(var+1e-5f);
    if (s==0) ln_s[c] = df*rs*ln_sg[c]+ln_sb[c];
  }
  __syncthreads();
  { // q
    float a0 = 0.f, a1 = 0.f;
    for(int pk=s*16; pk<s*16+16; pk+=2){
      ushort4_t wa = *reinterpret_cast<const ushort4_t*>(Wqp + ((size_t)pk*256 + c)*4);
      ushort4_t wb = *reinterpret_cast<const ushort4_t*>(Wqp + ((size_t)(pk+1)*256 + c)*4);
      a0 += bf2f(wa.x)*ln_s[4*pk] + bf2f(wa.y)*ln_s[4*pk+1]
          + bf2f(wa.z)*ln_s[4*pk+2] + bf2f(wa.w)*ln_s[4*pk+3];
      a1 += bf2f(wb.x)*ln_s[4*pk+4] + bf2f(wb.y)*ln_s[4*pk+5]
          + bf2f(wb.z)*ln_s[4*pk+6] + bf2f(wb.w)*ln_s[4*pk+7];
    }
    red_a[tid] = a0+a1;
  }
  __syncthreads();
  if (tid < 256) q_s[tid] = red_a[tid]+red_a[256+tid]+red_a[512+tid]+red_a[768+tid];
  __syncthreads();
  { // p
    int h = tid>>8;
    float a0 = 0.f, a1 = 0.f;
    for(int pd=0;pd<16;pd+=2){
      ushort4_t wa = *reinterpret_cast<const ushort4_t*>(Wkp + ((size_t)pd*1024 + tid)*4);
      ushort4_t wb = *reinterpret_cast<const ushort4_t*>(Wkp + ((size_t)(pd+1)*1024 + tid)*4);
      a0 += bf2f(wa.x)*q_s[h*64+4*pd] + bf2f(wa.y)*q_s[h*64+4*pd+1]
          + bf2f(wa.z)*q_s[h*64+4*pd+2] + bf2f(wa.w)*q_s[h*64+4*pd+3];
      a1 += bf2f(wb.x)*q_s[h*64+4*pd+4] + bf2f(wb.y)*q_s[h*64+4*pd+5]
          + bf2f(wb.z)*q_s[h*64+4*pd+6] + bf2f(wb.w)*q_s[h*64+4*pd+7];
    }
    p_s[tid] = 2.0f*(a0+a1);
  }
  __syncthreads();
  // ---- phase A (unroll-2 rows, DPP reductions) ----
  int wid = tid>>6, lane = tid&63;
  int grp = tid>>5, cl = tid&31;
  f32x2 pp2[4][4];
  #pragma unroll
  for(int h=0;h<4;h++)
    #pragma unroll
    for(int j2=0;j2<4;j2++){
      pp2[h][j2].x = p_s[h*256 + cl*8 + j2*2];
      pp2[h][j2].y = p_s[h*256 + cl*8 + j2*2 + 1];
    }
  f32x2 u2[4][4] = {};
  float wsum[4] = {0,0,0,0};
  const unsigned short* xb = x + ((size_t)b*N_ + split*ROWS)*256;
  for(int it=0; it<ROWS/64; ++it){
    int r0 = it*64 + grp, r1 = r0 + 32;
    uint4 xa = *reinterpret_cast<const uint4*>(xb + (size_t)r0*256 + cl*8);
    uint4 xc = *reinterpret_cast<const uint4*>(xb + (size_t)r1*256 + cl*8);
    f32x2 x0[4], x1[4];
    x0[0]=up2(xa.x); x0[1]=up2(xa.y); x0[2]=up2(xa.z); x0[3]=up2(xa.w);
    x1[0]=up2(xc.x); x1[1]=up2(xc.y); x1[2]=up2(xc.z); x1[3]=up2(xc.w);
    float w0[4], w1[4];
    #pragma unroll
    for(int h=0;h<4;h++){
      f32x2 da = x0[0]*pp2[h][0] + x0[2]*pp2[h][2];
      f32x2 db = x0[1]*pp2[h][1] + x0[3]*pp2[h][3];
      da += db;
      float d0 = da.x + da.y;
      f32x2 ea = x1[0]*pp2[h][0] + x1[2]*pp2[h][2];
      f32x2 eb = x1[1]*pp2[h][1] + x1[3]*pp2[h][3];
      ea += eb;
      float d1 = ea.x + ea.y;
      d0 = rsum32(d0);
      d1 = rsum32(d1);
      w0[h] = sigm(d0) + 1e-8f;
      w1[h] = sigm(d1) + 1e-8f;
      wsum[h] += w0[h] + w1[h];
    }
    #pragma unroll
    for(int h=0;h<4;h++){
      f32x2 wa; wa.x = w0[h]; wa.y = w0[h];
      f32x2 wb; wb.x = w1[h]; wb.y = w1[h];
      #pragma unroll
      for(int j2=0;j2<4;j2++){ u2[h][j2] += wa*x0[j2]; u2[h][j2] += wb*x1[j2]; }
    }
    if (write_w && cl==0){
      float4 wv; wv.x=w0[0]; wv.y=w0[1]; wv.z=w0[2]; wv.w=w0[3];
      *reinterpret_cast<float4*>(w_buf + ((size_t)b*N_ + split*ROWS + r0)*4) = wv;
      float4 wz; wz.x=w1[0]; wz.y=w1[1]; wz.z=w1[2]; wz.w=w1[3];
      *reinterpret_cast<float4*>(w_buf + ((size_t)b*N_ + split*ROWS + r1)*4) = wz;
    }
  }
  #pragma unroll
  for(int h=0;h<4;h++){
    #pragma unroll
    for(int j2=0;j2<4;j2++){
      u2[h][j2].x += __shfl_xor(u2[h][j2].x,32);
      u2[h][j2].y += __shfl_xor(u2[h][j2].y,32);
    }
    wsum[h] += __shfl_xor(wsum[h],32);
  }
  __syncthreads();
  if (wid < 8 && lane < 32){
    #pragma unroll
    for(int h=0;h<4;h++){
      float4 a; a.x=u2[h][0].x; a.y=u2[h][0].y; a.z=u2[h][1].x; a.w=u2[h][1].y;
      float4 cc; cc.x=u2[h][2].x; cc.y=u2[h][2].y; cc.z=u2[h][3].x; cc.w=u2[h][3].y;
      *reinterpret_cast<float4*>(&u_red[wid][h*256 + cl*8    ]) = a;
      *reinterpret_cast<float4*>(&u_red[wid][h*256 + cl*8 + 4]) = cc;
    }
  }
  if (lane==0){
    #pragma unroll
    for(int h=0;h<4;h++) ws_red[wid][h] = wsum[h];
  }
  __syncthreads();
  if (wid >= 8 && lane < 32){
    #pragma unroll
    for(int h=0;h<4;h++){
      float4 a = *reinterpret_cast<const float4*>(&u_red[wid-8][h*256 + cl*8]);
      float4 cc = *reinterpret_cast<const float4*>(&u_red[wid-8][h*256 + cl*8 + 4]);
      a.x+=u2[h][0].x; a.y+=u2[h][0].y; a.z+=u2[h][1].x; a.w+=u2[h][1].y;
      cc.x+=u2[h][2].x; cc.y+=u2[h][2].y; cc.z+=u2[h][3].x; cc.w+=u2[h][3].y;
      *reinterpret_cast<float4*>(&u_red[wid-8][h*256 + cl*8    ]) = a;
      *reinterpret_cast<float4*>(&u_red[wid-8][h*256 + cl*8 + 4]) = cc;
    }
  }
  __syncthreads();
  {
    float sm = 0.f;
    #pragma unroll
    for(int w=0;w<8;w++) sm += u_red[w][tid];
    u_out[((size_t)split*128 + b)*1024 + tid] = sm;
  }
  if (tid < 4){
    float sm = 0.f;
    #pragma unroll
    for(int w=0;w<16;w++) sm += ws_red[w][tid];
    ws_out[((size_t)split*128 + b)*4 + tid] = sm;
  }
}

// ---------------- final step ----------------------------------------------
__global__ __launch_bounds__(1024) void k_finstep(
    const float* __restrict__ u_in, const float* __restrict__ ws_in,
    const float* __restrict__ rep_in,
    const unsigned short* __restrict__ Wvp, const unsigned short* __restrict__ Wip,
    const unsigned short* __restrict__ Whp, const float* __restrict__ bih,
    const float* __restrict__ bhh, const float* __restrict__ ln_rg,
    const float* __restrict__ ln_rb, const unsigned short* __restrict__ W1p,
    const unsigned short* __restrict__ W2p, const float* __restrict__ b2,
    float* __restrict__ out_rep, float* __restrict__ wsum_tot, int nsp_in){
  __shared__ float u_s[1024];
  __shared__ float att_s[256], rep_s[256], ln_s[256], nw_s[256];
  __shared__ float gi_s[768], gh_s[768];
  __shared__ float h1_s[1024], red_a[1024];
  __shared__ float ws_s[4]; __shared__ float s16[16];
  int b = blockIdx.x;
  int tid = threadIdx.x;
  int c = tid & 255, s = tid >> 8;
  {
    float acc = 0.f;
    for(int sp=0; sp<nsp_in; ++sp)
      acc += u_in[((size_t)sp*128 + b)*1024 + tid];
    u_s[tid] = acc;
    if (tid < 4){
      float w = 0.f;
      for(int sp=0; sp<nsp_in; ++sp) w += ws_in[((size_t)sp*128 + b)*4 + tid];
      ws_s[tid] = w; wsum_tot[b*4 + tid] = w;
    }
    if (tid < 256) rep_s[tid] = rep_in[b*256 + tid];
  }
  __syncthreads();
  {
    const float* uh = u_s + (c>>6)*256;
    float a0 = 0.f, a1 = 0.f;
    for(int pk=s*16; pk<s*16+16; pk+=2){
      ushort4_t wa = *reinterpret_cast<const ushort4_t*>(Wvp + ((size_t)pk*256 + c)*4);
      ushort4_t wb = *reinterpret_cast<const ushort4_t*>(Wvp + ((size_t)(pk+1)*256 + c)*4);
      a0 += bf2f(wa.x)*uh[4*pk] + bf2f(wa.y)*uh[4*pk+1]
          + bf2f(wa.z)*uh[4*pk+2] + bf2f(wa.w)*uh[4*pk+3];
      a1 += bf2f(wb.x)*uh[4*pk+4] + bf2f(wb.y)*uh[4*pk+5]
          + bf2f(wb.z)*uh[4*pk+6] + bf2f(wb.w)*uh[4*pk+7];
    }
    red_a[tid] = a0+a1;
  }
  __syncthreads();
  if (tid < 256) att_s[tid] = (red_a[tid]+red_a[256+tid]+red_a[512+tid]+red_a[768+tid]) / ws_s[tid>>6];
  __syncthreads();
  if (tid < 768){
    float gi0=0.f, gi1=0.f, gh0=0.f, gh1=0.f;
    for(int pk=0;pk<64;pk+=2){
      ushort4_t wi0 = *reinterpret_cast<const ushort4_t*>(Wip + ((size_t)pk*768 + tid)*4);
      ushort4_t wh0 = *reinterpret_cast<const ushort4_t*>(Whp + ((size_t)pk*768 + tid)*4);
      ushort4_t wi1 = *reinterpret_cast<const ushort4_t*>(Wip + ((size_t)(pk+1)*768 + tid)*4);
      ushort4_t wh1 = *reinterpret_cast<const ushort4_t*>(Whp + ((size_t)(pk+1)*768 + tid)*4);
      gi0 += bf2f(wi0.x)*att_s[4*pk] + bf2f(wi0.y)*att_s[4*pk+1]
           + bf2f(wi0.z)*att_s[4*pk+2] + bf2f(wi0.w)*att_s[4*pk+3];
      gh0 += bf2f(wh0.x)*rep_s[4*pk] + bf2f(wh0.y)*rep_s[4*pk+1]
           + bf2f(wh0.z)*rep_s[4*pk+2] + bf2f(wh0.w)*rep_s[4*pk+3];
      gi1 += bf2f(wi1.x)*att_s[4*pk+4] + bf2f(wi1.y)*att_s[4*pk+5]
           + bf2f(wi1.z)*att_s[4*pk+6] + bf2f(wi1.w)*att_s[4*pk+7];
      gh1 += bf2f(wh1.x)*rep_s[4*pk+4] + bf2f(wh1.y)*rep_s[4*pk+5]
           + bf2f(wh1.z)*rep_s[4*pk+6] + bf2f(wh1.w)*rep_s[4*pk+7];
    }
    gi_s[tid] = gi0+gi1 + bih[tid];
    gh_s[tid] = gh0+gh1 + bhh[tid];
  }
  __syncthreads();
  if (tid < 256){
    float rr = sigm(gi_s[tid]     + gh_s[tid]);
    float zz = sigm(gi_s[256+tid] + gh_s[256+tid]);
    float t3 = tanhf(gi_s[512+tid] + rr*gh_s[512+tid]);
    nw_s[tid] = (1.f-zz)*t3 + zz*rep_s[tid];
  }
  __syncthreads();
  {
    float v = nw_s[c];
    float mu = blkSum16(v, s16)*(1.0f/1024.0f);
    float df = v - mu;
    float var = blkSum16(df*df, s16)*(1.0f/1024.0f);
    float rs = rsqrtf(var+1e-5f);
    if (s==0) ln_s[c] = df*rs*ln_rg[c]+ln_rb[c];
  }
  __syncthreads();
  {
    float a0 = 0.f, a1 = 0.f;
    for(int pk=0;pk<64;pk+=2){
      ushort4_t wa = *reinterpret_cast<const ushort4_t*>(W1p + ((size_t)pk*1024 + tid)*4);
      ushort4_t wb = *reinterpret_cast<const ushort4_t*>(W1p + ((size_t)(pk+1)*1024 + tid)*4);
      a0 += bf2f(wa.x)*ln_s[4*pk] + bf2f(wa.y)*ln_s[4*pk+1]
          + bf2f(wa.z)*ln_s[4*pk+2] + bf2f(wa.w)*ln_s[4*pk+3];
      a1 += bf2f(wb.x)*ln_s[4*pk+4] + bf2f(wb.y)*ln_s[4*pk+5]
          + bf2f(wb.z)*ln_s[4*pk+6] + bf2f(wb.w)*ln_s[4*pk+7];
    }
    h1_s[tid] = fmaxf(a0+a1, 0.f);
  }
  __syncthreads();
  {
    float a0 = 0.f, a1 = 0.f;
    for(int pk=s*64; pk<s*64+64; pk+=2){
      ushort4_t wa = *reinterpret_cast<const ushort4_t*>(W2p + ((size_t)pk*256 + c)*4);
      ushort4_t wb = *reinterpret_cast<const ushort4_t*>(W2p + ((size_t)(pk+1)*256 + c)*4);
      a0 += bf2f(wa.x)*h1_s[4*pk] + bf2f(wa.y)*h1_s[4*pk+1]
          + bf2f(wa.z)*h1_s[4*pk+2] + bf2f(wa.w)*h1_s[4*pk+3];
      a1 += bf2f(wb.x)*h1_s[4*pk+4] + bf2f(wb.y)*h1_s[4*pk+5]
          + bf2f(wb.z)*h1_s[4*pk+6] + bf2f(wb.w)*h1_s[4*pk+7];
    }
    red_a[tid] = a0+a1;
  }
  __syncthreads();
  if (tid < 256){
    float rn = nw_s[tid] + (red_a[tid]+red_a[256+tid]+red_a[512+tid]+red_a[768+tid]) + b2[tid];
    out_rep[b*256+tid] = rn;
  }
}

// ---------------- final w output ------------------------------------------
__global__ __launch_bounds__(256) void k_wout(
    const float* __restrict__ w_buf, const float* __restrict__ wsum_tot,
    float* __restrict__ out){
  int idx = blockIdx.x*256 + threadIdx.x;     // 0..524287
  int b = idx>>12;
  float4 w4 = *reinterpret_cast<const float4*>(w_buf + (size_t)idx*4);
  out[idx] = w4.x/wsum_tot[b*4+0] + w4.y/wsum_tot[b*4+1]
           + w4.z/wsum_tot[b*4+2] + w4.w/wsum_tot[b*4+3];
}

extern "C" void kernel_launch(void* const* d_in, const int* in_sizes, int n_in,
                              void* d_out, int out_size, void* d_ws, size_t ws_size,
                              hipStream_t stream){
  const float* inputs  = (const float*)d_in[0];
  const float* eps     = (const float*)d_in[1];
  const float* init_mu = (const float*)d_in[2];
  const float* init_lv = (const float*)d_in[3];
  const float* Wk      = (const float*)d_in[4];
  const float* Wv      = (const float*)d_in[5];
  const float* Wq      = (const float*)d_in[6];
  const float* ln_in_g = (const float*)d_in[7];
  const float* ln_in_b = (const float*)d_in[8];
  const float* ln_sg   = (const float*)d_in[9];
  const float* ln_sb   = (const float*)d_in[10];
  const float* ln_rg   = (const float*)d_in[11];
  const float* ln_rb   = (const float*)d_in[12];
  const float* Wih     = (const float*)d_in[13];
  const float* Whh     = (const float*)d_in[14];
  const float* bih     = (const float*)d_in[15];
  const float* bhh     = (const float*)d_in[16];
  const float* W1      = (const float*)d_in[17];
  const float* W2      = (const float*)d_in[18];
  const float* b2      = (const float*)d_in[19];

  char* ws = (char*)d_ws;
  size_t off = 0;
  auto alloc = [&](size_t bytes)->void*{
    void* p = ws + off; off += (bytes + 255) & ~(size_t)255; return p;
  };
  unsigned short* x   = (unsigned short*)alloc((size_t)128*N_*256*2);
  unsigned short* Wvp = (unsigned short*)alloc(65536*2);
  unsigned short* Wip = (unsigned short*)alloc(196608*2);
  unsigned short* Whp = (unsigned short*)alloc(196608*2);
  unsigned short* W1p = (unsigned short*)alloc(262144*2);
  unsigned short* W2p = (unsigned short*)alloc(262144*2);
  unsigned short* Wqp = (unsigned short*)alloc(65536*2);
  unsigned short* Wkp = (unsigned short*)alloc(65536*2);
  float* p0    = (float*)alloc((size_t)128*1024*4);
  float* uA    = (float*)alloc((size_t)NSPL1*128*1024*4);
  float* uB    = (float*)alloc((size_t)NSPL1*128*1024*4);
  float* wsA   = (float*)alloc(NSPL1*128*4*4);
  float* wsB   = (float*)alloc(NSPL1*128*4*4);
  float* repA  = (float*)alloc(128*256*4);
  float* repB  = (float*)alloc(128*256*4);
  float* wsum_tot = (float*)alloc(512*4);
  float* w_buf = (float*)alloc((size_t)128*N_*4*4);

  float* out_rep = (float*)d_out;
  float* out_w   = out_rep + 128*256;

  k_prep<<<1024,256,0,stream>>>(Wv,Wih,Whh,W1,W2,Wq,Wk, Wvp,Wip,Whp,W1p,W2p,Wqp,Wkp);
  k_init<<<128,256,0,stream>>>(eps, init_mu, init_lv, ln_sg, ln_sb, Wq, Wkp, repA, p0);
  k_lnattn<<<dim3(NSPL1,128),1024,0,stream>>>(inputs, ln_in_g, ln_in_b, p0, x, uA, wsA);
  k_attnstep<<<dim3(NSPL2,128),1024,0,stream>>>(x, uA, wsA, repA, repB,
      Wvp,Wip,Whp,bih,bhh,ln_rg,ln_rb,W1p,W2p,b2,ln_sg,ln_sb,Wqp,Wkp,
      uB, wsB, w_buf, 0, NSPL1);
  k_attnstep<<<dim3(NSPL2,128),1024,0,stream>>>(x, uB, wsB, repB, repA,
      Wvp,Wip,Whp,bih,bhh,ln_rg,ln_rb,W1p,W2p,b2,ln_sg,ln_sb,Wqp,Wkp,
      uA, wsA, w_buf, 0, NSPL2);
  k_attnstep<<<dim3(NSPL2,128),1024,0,stream>>>(x, uA, wsA, repA, repB,
      Wvp,Wip,Whp,bih,bhh,ln_rg,ln_rb,W1p,W2p,b2,ln_sg,ln_sb,Wqp,Wkp,
      uB, wsB, w_buf, 1, NSPL2);
  k_finstep<<<128,1024,0,stream>>>(uB, wsB, repB,
      Wvp,Wip,Whp,bih,bhh,ln_rg,ln_rb,W1p,W2p,b2, out_rep, wsum_tot, NSPL2);
  k_wout<<<2048,256,0,stream>>>(w_buf, wsum_tot, out_w);
}

// Round 10
// 546.956 us; speedup vs baseline: 1.3415x; 1.3415x over previous
//
#include <hip/hip_runtime.h>
#include <hip/hip_bf16.h>

typedef __attribute__((ext_vector_type(2))) float f32x2;
typedef __attribute__((ext_vector_type(8))) unsigned short ushort8;
typedef __attribute__((ext_vector_type(4))) unsigned short ushort4_t;

#define N_    4096
#define NSPL1 2
#define NSPL2 2

__device__ inline float bf2f(unsigned short u){
  union{unsigned int i; float f;} c; c.i = ((unsigned int)u)<<16; return c.f;
}
__device__ inline unsigned short f2bf(float f){
  union{float f; unsigned int i;} c; c.f = f;
  unsigned int x = c.i;
  return (unsigned short)((x + 0x7fffu + ((x>>16)&1u)) >> 16);
}
__device__ inline float sigm(float s){ return 1.0f/(1.0f+__expf(-s)); }
__device__ inline f32x2 up2(unsigned int w){
  union{unsigned int i; float f;} lo, hi;
  lo.i = w<<16; hi.i = w & 0xffff0000u;
  f32x2 r; r.x = lo.f; r.y = hi.f; return r;
}

// 32-lane group sum via DPP row_ror (VALU pipe) + one cross-16 shuffle.
__device__ inline float rsum32(float v){
  union{float f; int i;} a, t;
  a.f = v;
  t.i = __builtin_amdgcn_update_dpp(0, a.i, 0x121, 0xF, 0xF, true); a.f += t.f;
  t.i = __builtin_amdgcn_update_dpp(0, a.i, 0x122, 0xF, 0xF, true); a.f += t.f;
  t.i = __builtin_amdgcn_update_dpp(0, a.i, 0x124, 0xF, 0xF, true); a.f += t.f;
  t.i = __builtin_amdgcn_update_dpp(0, a.i, 0x128, 0xF, 0xF, true); a.f += t.f;
  a.f += __shfl_xor(a.f, 16);
  return a.f;
}

// block = 256 threads (4 waves). Full block sum.
__device__ inline float blkSum(float v, float* s4){
  v += __shfl_xor(v,1);  v += __shfl_xor(v,2);  v += __shfl_xor(v,4);
  v += __shfl_xor(v,8);  v += __shfl_xor(v,16); v += __shfl_xor(v,32);
  int lane = threadIdx.x & 63, w = threadIdx.x >> 6;
  __syncthreads();
  if (lane==0) s4[w] = v;
  __syncthreads();
  return s4[0]+s4[1]+s4[2]+s4[3];
}

// block = 1024 threads (16 waves). Full block sum.
__device__ inline float blkSum16(float v, float* s16){
  #pragma unroll
  for(int o=1;o<64;o<<=1) v += __shfl_xor(v,o);
  int lane = threadIdx.x & 63, w = threadIdx.x >> 6;
  __syncthreads();
  if (lane==0) s16[w] = v;
  __syncthreads();
  float r = 0.f;
  #pragma unroll
  for(int i=0;i<16;i++) r += s16[i];
  return r;
}

// ---------------- prep: packed-k bf16 weights -----------------------------
__global__ __launch_bounds__(256) void k_prep(
    const float* __restrict__ Wv, const float* __restrict__ Wih,
    const float* __restrict__ Whh, const float* __restrict__ W1,
    const float* __restrict__ W2, const float* __restrict__ Wq,
    const float* __restrict__ Wk,
    unsigned short* __restrict__ Wvp, unsigned short* __restrict__ Wip,
    unsigned short* __restrict__ Whp, unsigned short* __restrict__ W1p,
    unsigned short* __restrict__ W2p, unsigned short* __restrict__ Wqp,
    unsigned short* __restrict__ Wkp){
  int e = blockIdx.x*256 + threadIdx.x;          // 0 .. 262143
  if (e < 65536){
    int i = e&3, j = (e>>2)&255, pk = e>>10;
    Wvp[e] = f2bf(Wv[(4*pk+i)*256 + j]);
    Wqp[e] = f2bf(Wq[(4*pk+i)*256 + j]);
  }
  if (e < 196608){
    int i = e&3, j2 = e>>2;
    int j = j2 % 768, pk = j2 / 768;
    Wip[e] = f2bf(Wih[j*256 + 4*pk+i]);
    Whp[e] = f2bf(Whh[j*256 + 4*pk+i]);
  }
  {
    int i = e&3, j = (e>>2)&1023, pk = e>>12;
    W1p[e] = f2bf(W1[(4*pk+i)*1024 + j]);
  }
  {
    int i = e&3, j = (e>>2)&255, pk = e>>10;
    W2p[e] = f2bf(W2[(4*pk+i)*256 + j]);
  }
  if (e < 65536){
    int i = e&3, hc = (e>>2)&1023, pd = e>>12;
    int h = hc>>8, c = hc&255;
    Wkp[e] = f2bf(Wk[c*256 + h*64 + 4*pd+i]);
  }
}

// ---------------- init: rep0 = mu + exp(.5 lv)*eps ; q0 -> p0 -------------
__global__ __launch_bounds__(256) void k_init(
    const float* __restrict__ eps, const float* __restrict__ mu0,
    const float* __restrict__ lv0, const float* __restrict__ sg,
    const float* __restrict__ sb, const float* __restrict__ Wq,
    const unsigned short* __restrict__ Wkp,
    float* __restrict__ rep, float* __restrict__ p_out){
  __shared__ float s4[4]; __shared__ float xq[256]; __shared__ float q_s[256];
  int b = blockIdx.x, c = threadIdx.x;
  float r0 = mu0[c] + __expf(0.5f*lv0[c]) * eps[b*256+c];
  rep[b*256+c] = r0;
  float mu = blkSum(r0, s4) * (1.0f/256.0f);
  float df = r0 - mu;
  float var = blkSum(df*df, s4) * (1.0f/256.0f);
  float rs = rsqrtf(var + 1e-5f);
  xq[c] = df*rs*sg[c] + sb[c];
  __syncthreads();
  float a0=0,a1=0,a2=0,a3=0;
  for(int k=0;k<256;k+=4){
    a0 += xq[k  ]*Wq[(k  )*256+c];
    a1 += xq[k+1]*Wq[(k+1)*256+c];
    a2 += xq[k+2]*Wq[(k+2)*256+c];
    a3 += xq[k+3]*Wq[(k+3)*256+c];
  }
  q_s[c] = a0+a1+a2+a3;
  __syncthreads();
  #pragma unroll
  for(int h=0;h<4;h++){
    float acc = 0.f;
    for(int pd=0;pd<16;pd++){
      ushort4_t w4 = *reinterpret_cast<const ushort4_t*>(Wkp + ((size_t)pd*1024 + h*256 + c)*4);
      acc += bf2f(w4.x)*q_s[h*64+4*pd  ] + bf2f(w4.y)*q_s[h*64+4*pd+1]
           + bf2f(w4.z)*q_s[h*64+4*pd+2] + bf2f(w4.w)*q_s[h*64+4*pd+3];
    }
    p_out[b*1024 + h*256 + c] = 2.0f*acc;
  }
}

// ---------------- fused input-LN + attention pass 1 -----------------------
// grid (NSPL1,128) x 1024 thr; depth-1 register prefetch of next rows.
__global__ __launch_bounds__(1024) void k_lnattn(
    const float* __restrict__ in, const float* __restrict__ g,
    const float* __restrict__ bln, const float* __restrict__ p,
    unsigned short* __restrict__ x,
    float* __restrict__ u_part, float* __restrict__ ws_part){
  __shared__ float u_red[8][1024];
  __shared__ float ws_red[16][4];
  int split = blockIdx.x, b = blockIdx.y;
  int tid = threadIdx.x, wid = tid>>6, lane = tid&63;
  int grp = tid>>5, cl = tid&31;
  const int ROWS = N_ / NSPL1;            // 2048
  const int NIT = ROWS/64;                // 32
  const float* pb = p + (size_t)b*1024;
  f32x2 pp2[4][4];
  #pragma unroll
  for(int h=0;h<4;h++){
    float4 pa = *reinterpret_cast<const float4*>(pb + h*256 + cl*8);
    float4 pc = *reinterpret_cast<const float4*>(pb + h*256 + cl*8 + 4);
    pp2[h][0] = f32x2{pa.x,pa.y}; pp2[h][1] = f32x2{pa.z,pa.w};
    pp2[h][2] = f32x2{pc.x,pc.y}; pp2[h][3] = f32x2{pc.z,pc.w};
  }
  float gg[8], bb[8];
  {
    float4 a = *reinterpret_cast<const float4*>(g + cl*8);
    float4 c = *reinterpret_cast<const float4*>(g + cl*8 + 4);
    gg[0]=a.x; gg[1]=a.y; gg[2]=a.z; gg[3]=a.w; gg[4]=c.x; gg[5]=c.y; gg[6]=c.z; gg[7]=c.w;
    a = *reinterpret_cast<const float4*>(bln + cl*8);
    c = *reinterpret_cast<const float4*>(bln + cl*8 + 4);
    bb[0]=a.x; bb[1]=a.y; bb[2]=a.z; bb[3]=a.w; bb[4]=c.x; bb[5]=c.y; bb[6]=c.z; bb[7]=c.w;
  }
  f32x2 u[4][4] = {};
  float wsum[4] = {0,0,0,0};
  const float* inb = in + ((size_t)b*N_ + split*ROWS)*256;
  unsigned short* xb = x + ((size_t)b*N_ + split*ROWS)*256;
  // prefetch iter 0
  float4 a0 = *reinterpret_cast<const float4*>(inb + (size_t)grp*256 + cl*8);
  float4 c0 = *reinterpret_cast<const float4*>(inb + (size_t)grp*256 + cl*8 + 4);
  float4 a1 = *reinterpret_cast<const float4*>(inb + (size_t)(grp+32)*256 + cl*8);
  float4 c1 = *reinterpret_cast<const float4*>(inb + (size_t)(grp+32)*256 + cl*8 + 4);
  for(int it=0; it<NIT; ++it){
    int r0 = it*64 + grp, r1 = r0 + 32;
    float4 na, nc, nb1, nd1;
    if (it+1 < NIT){
      int p0 = (it+1)*64 + grp, p1 = p0 + 32;
      na  = *reinterpret_cast<const float4*>(inb + (size_t)p0*256 + cl*8);
      nc  = *reinterpret_cast<const float4*>(inb + (size_t)p0*256 + cl*8 + 4);
      nb1 = *reinterpret_cast<const float4*>(inb + (size_t)p1*256 + cl*8);
      nd1 = *reinterpret_cast<const float4*>(inb + (size_t)p1*256 + cl*8 + 4);
    }
    float sm0 = a0.x+a0.y+a0.z+a0.w + c0.x+c0.y+c0.z+c0.w;
    float sq0 = a0.x*a0.x+a0.y*a0.y+a0.z*a0.z+a0.w*a0.w
              + c0.x*c0.x+c0.y*c0.y+c0.z*c0.z+c0.w*c0.w;
    float sm1 = a1.x+a1.y+a1.z+a1.w + c1.x+c1.y+c1.z+c1.w;
    float sq1 = a1.x*a1.x+a1.y*a1.y+a1.z*a1.z+a1.w*a1.w
              + c1.x*c1.x+c1.y*c1.y+c1.z*c1.z+c1.w*c1.w;
    sm0 = rsum32(sm0); sq0 = rsum32(sq0);
    sm1 = rsum32(sm1); sq1 = rsum32(sq1);
    float mu0 = sm0*(1.0f/256.0f);
    float rs0 = rsqrtf(sq0*(1.0f/256.0f) - mu0*mu0 + 1e-5f);
    float mu1 = sm1*(1.0f/256.0f);
    float rs1 = rsqrtf(sq1*(1.0f/256.0f) - mu1*mu1 + 1e-5f);
    f32x2 px0[4], px1[4];
    px0[0].x=(a0.x-mu0)*rs0*gg[0]+bb[0]; px0[0].y=(a0.y-mu0)*rs0*gg[1]+bb[1];
    px0[1].x=(a0.z-mu0)*rs0*gg[2]+bb[2]; px0[1].y=(a0.w-mu0)*rs0*gg[3]+bb[3];
    px0[2].x=(c0.x-mu0)*rs0*gg[4]+bb[4]; px0[2].y=(c0.y-mu0)*rs0*gg[5]+bb[5];
    px0[3].x=(c0.z-mu0)*rs0*gg[6]+bb[6]; px0[3].y=(c0.w-mu0)*rs0*gg[7]+bb[7];
    px1[0].x=(a1.x-mu1)*rs1*gg[0]+bb[0]; px1[0].y=(a1.y-mu1)*rs1*gg[1]+bb[1];
    px1[1].x=(a1.z-mu1)*rs1*gg[2]+bb[2]; px1[1].y=(a1.w-mu1)*rs1*gg[3]+bb[3];
    px1[2].x=(c1.x-mu1)*rs1*gg[4]+bb[4]; px1[2].y=(c1.y-mu1)*rs1*gg[5]+bb[5];
    px1[3].x=(c1.z-mu1)*rs1*gg[6]+bb[6]; px1[3].y=(c1.w-mu1)*rs1*gg[7]+bb[7];
    ushort8 o8;
    o8[0]=f2bf(px0[0].x); o8[1]=f2bf(px0[0].y); o8[2]=f2bf(px0[1].x); o8[3]=f2bf(px0[1].y);
    o8[4]=f2bf(px0[2].x); o8[5]=f2bf(px0[2].y); o8[6]=f2bf(px0[3].x); o8[7]=f2bf(px0[3].y);
    *reinterpret_cast<ushort8*>(xb + (size_t)r0*256 + cl*8) = o8;
    o8[0]=f2bf(px1[0].x); o8[1]=f2bf(px1[0].y); o8[2]=f2bf(px1[1].x); o8[3]=f2bf(px1[1].y);
    o8[4]=f2bf(px1[2].x); o8[5]=f2bf(px1[2].y); o8[6]=f2bf(px1[3].x); o8[7]=f2bf(px1[3].y);
    *reinterpret_cast<ushort8*>(xb + (size_t)r1*256 + cl*8) = o8;
    float w0[4], w1[4];
    #pragma unroll
    for(int h=0;h<4;h++){
      f32x2 da = px0[0]*pp2[h][0] + px0[2]*pp2[h][2];
      f32x2 db = px0[1]*pp2[h][1] + px0[3]*pp2[h][3];
      da += db;
      float d0 = da.x + da.y;
      f32x2 ea = px1[0]*pp2[h][0] + px1[2]*pp2[h][2];
      f32x2 eb = px1[1]*pp2[h][1] + px1[3]*pp2[h][3];
      ea += eb;
      float d1 = ea.x + ea.y;
      d0 = rsum32(d0);
      d1 = rsum32(d1);
      w0[h] = sigm(d0) + 1e-8f;
      w1[h] = sigm(d1) + 1e-8f;
      wsum[h] += w0[h] + w1[h];
    }
    #pragma unroll
    for(int h=0;h<4;h++){
      f32x2 wa; wa.x = w0[h]; wa.y = w0[h];
      f32x2 wb; wb.x = w1[h]; wb.y = w1[h];
      #pragma unroll
      for(int j=0;j<4;j++){ u[h][j] += wa*px0[j]; u[h][j] += wb*px1[j]; }
    }
    a0 = na; c0 = nc; a1 = nb1; c1 = nd1;
  }
  #pragma unroll
  for(int h=0;h<4;h++){
    #pragma unroll
    for(int j=0;j<4;j++){
      u[h][j].x += __shfl_xor(u[h][j].x,32);
      u[h][j].y += __shfl_xor(u[h][j].y,32);
    }
    wsum[h] += __shfl_xor(wsum[h],32);
  }
  if (wid < 8 && lane < 32){
    #pragma unroll
    for(int h=0;h<4;h++){
      float4 a; a.x=u[h][0].x; a.y=u[h][0].y; a.z=u[h][1].x; a.w=u[h][1].y;
      float4 c; c.x=u[h][2].x; c.y=u[h][2].y; c.z=u[h][3].x; c.w=u[h][3].y;
      *reinterpret_cast<float4*>(&u_red[wid][h*256 + cl*8    ]) = a;
      *reinterpret_cast<float4*>(&u_red[wid][h*256 + cl*8 + 4]) = c;
    }
  }
  if (lane==0){
    #pragma unroll
    for(int h=0;h<4;h++) ws_red[wid][h] = wsum[h];
  }
  __syncthreads();
  if (wid >= 8 && lane < 32){
    #pragma unroll
    for(int h=0;h<4;h++){
      float4 a = *reinterpret_cast<const float4*>(&u_red[wid-8][h*256 + cl*8]);
      float4 c = *reinterpret_cast<const float4*>(&u_red[wid-8][h*256 + cl*8 + 4]);
      a.x+=u[h][0].x; a.y+=u[h][0].y; a.z+=u[h][1].x; a.w+=u[h][1].y;
      c.x+=u[h][2].x; c.y+=u[h][2].y; c.z+=u[h][3].x; c.w+=u[h][3].y;
      *reinterpret_cast<float4*>(&u_red[wid-8][h*256 + cl*8    ]) = a;
      *reinterpret_cast<float4*>(&u_red[wid-8][h*256 + cl*8 + 4]) = c;
    }
  }
  __syncthreads();
  {
    float s = 0.f;
    #pragma unroll
    for(int w=0;w<8;w++) s += u_red[w][tid];
    u_part[((size_t)split*128 + b)*1024 + tid] = s;
  }
  if (tid < 4){
    float s = 0.f;
    #pragma unroll
    for(int w=0;w<16;w++) s += ws_red[w][tid];
    ws_part[((size_t)split*128 + b)*4 + tid] = s;
  }
}

// ---------------- fused step + attention pass -----------------------------
__global__ __launch_bounds__(1024) void k_attnstep(
    const unsigned short* __restrict__ x,
    const float* __restrict__ u_in, const float* __restrict__ ws_in,
    const float* __restrict__ rep_in, float* __restrict__ rep_out,
    const unsigned short* __restrict__ Wvp, const unsigned short* __restrict__ Wip,
    const unsigned short* __restrict__ Whp, const float* __restrict__ bih,
    const float* __restrict__ bhh, const float* __restrict__ ln_rg,
    const float* __restrict__ ln_rb, const unsigned short* __restrict__ W1p,
    const unsigned short* __restrict__ W2p, const float* __restrict__ b2,
    const float* __restrict__ ln_sg, const float* __restrict__ ln_sb,
    const unsigned short* __restrict__ Wqp, const unsigned short* __restrict__ Wkp,
    float* __restrict__ u_out, float* __restrict__ ws_out,
    float* __restrict__ w_buf, int write_w, int nsp_in){
  __shared__ float u_s[1024];
  __shared__ float att_s[256], rep_s[256], ln_s[256], nw_s[256], q_s[256];
  __shared__ float gi_s[768], gh_s[768];
  __shared__ float h1_s[1024], p_s[1024], red_a[1024];
  __shared__ float ws_s[4]; __shared__ float s16[16];
  __shared__ float u_red[8][1024];
  __shared__ float ws_red[16][4];
  int split = blockIdx.x, b = blockIdx.y;
  int tid = threadIdx.x;
  int c = tid & 255, s = tid >> 8;
  const int ROWS = N_ / NSPL2;            // 2048
  const int NIT = ROWS/64;                // 32
  // ---- phase S ----
  {
    float acc = 0.f;
    for(int sp=0; sp<nsp_in; ++sp)
      acc += u_in[((size_t)sp*128 + b)*1024 + tid];
    u_s[tid] = acc;
    if (tid < 4){
      float w = 0.f;
      for(int sp=0; sp<nsp_in; ++sp) w += ws_in[((size_t)sp*128 + b)*4 + tid];
      ws_s[tid] = w;
    }
    if (tid < 256) rep_s[tid] = rep_in[b*256 + tid];
  }
  __syncthreads();
  { // att partial
    const float* uh = u_s + (c>>6)*256;
    float a0 = 0.f, a1 = 0.f;
    for(int pk=s*16; pk<s*16+16; pk+=2){
      ushort4_t wa = *reinterpret_cast<const ushort4_t*>(Wvp + ((size_t)pk*256 + c)*4);
      ushort4_t wb = *reinterpret_cast<const ushort4_t*>(Wvp + ((size_t)(pk+1)*256 + c)*4);
      a0 += bf2f(wa.x)*uh[4*pk] + bf2f(wa.y)*uh[4*pk+1]
          + bf2f(wa.z)*uh[4*pk+2] + bf2f(wa.w)*uh[4*pk+3];
      a1 += bf2f(wb.x)*uh[4*pk+4] + bf2f(wb.y)*uh[4*pk+5]
          + bf2f(wb.z)*uh[4*pk+6] + bf2f(wb.w)*uh[4*pk+7];
    }
    red_a[tid] = a0+a1;
  }
  __syncthreads();
  if (tid < 256) att_s[tid] = (red_a[tid]+red_a[256+tid]+red_a[512+tid]+red_a[768+tid]) / ws_s[tid>>6];
  __syncthreads();
  if (tid < 768){ // GRU rows
    float gi0=0.f, gi1=0.f, gh0=0.f, gh1=0.f;
    for(int pk=0;pk<64;pk+=2){
      ushort4_t wi0 = *reinterpret_cast<const ushort4_t*>(Wip + ((size_t)pk*768 + tid)*4);
      ushort4_t wh0 = *reinterpret_cast<const ushort4_t*>(Whp + ((size_t)pk*768 + tid)*4);
      ushort4_t wi1 = *reinterpret_cast<const ushort4_t*>(Wip + ((size_t)(pk+1)*768 + tid)*4);
      ushort4_t wh1 = *reinterpret_cast<const ushort4_t*>(Whp + ((size_t)(pk+1)*768 + tid)*4);
      gi0 += bf2f(wi0.x)*att_s[4*pk] + bf2f(wi0.y)*att_s[4*pk+1]
           + bf2f(wi0.z)*att_s[4*pk+2] + bf2f(wi0.w)*att_s[4*pk+3];
      gh0 += bf2f(wh0.x)*rep_s[4*pk] + bf2f(wh0.y)*rep_s[4*pk+1]
           + bf2f(wh0.z)*rep_s[4*pk+2] + bf2f(wh0.w)*rep_s[4*pk+3];
      gi1 += bf2f(wi1.x)*att_s[4*pk+4] + bf2f(wi1.y)*att_s[4*pk+5]
           + bf2f(wi1.z)*att_s[4*pk+6] + bf2f(wi1.w)*att_s[4*pk+7];
      gh1 += bf2f(wh1.x)*rep_s[4*pk+4] + bf2f(wh1.y)*rep_s[4*pk+5]
           + bf2f(wh1.z)*rep_s[4*pk+6] + bf2f(wh1.w)*rep_s[4*pk+7];
    }
    gi_s[tid] = gi0+gi1 + bih[tid];
    gh_s[tid] = gh0+gh1 + bhh[tid];
  }
  __syncthreads();
  if (tid < 256){
    float rr = sigm(gi_s[tid]     + gh_s[tid]);
    float zz = sigm(gi_s[256+tid] + gh_s[256+tid]);
    float t3 = tanhf(gi_s[512+tid] + rr*gh_s[512+tid]);
    nw_s[tid] = (1.f-zz)*t3 + zz*rep_s[tid];
  }
  __syncthreads();
  { // residual LN
    float v = nw_s[c];
    float mu = blkSum16(v, s16)*(1.0f/1024.0f);
    float df = v - mu;
    float var = blkSum16(df*df, s16)*(1.0f/1024.0f);
    float rs = rsqrtf(var+1e-5f);
    if (s==0) ln_s[c] = df*rs*ln_rg[c]+ln_rb[c];
  }
  __syncthreads();
  { // W1
    float a0 = 0.f, a1 = 0.f;
    for(int pk=0;pk<64;pk+=2){
      ushort4_t wa = *reinterpret_cast<const ushort4_t*>(W1p + ((size_t)pk*1024 + tid)*4);
      ushort4_t wb = *reinterpret_cast<const ushort4_t*>(W1p + ((size_t)(pk+1)*1024 + tid)*4);
      a0 += bf2f(wa.x)*ln_s[4*pk] + bf2f(wa.y)*ln_s[4*pk+1]
          + bf2f(wa.z)*ln_s[4*pk+2] + bf2f(wa.w)*ln_s[4*pk+3];
      a1 += bf2f(wb.x)*ln_s[4*pk+4] + bf2f(wb.y)*ln_s[4*pk+5]
          + bf2f(wb.z)*ln_s[4*pk+6] + bf2f(wb.w)*ln_s[4*pk+7];
    }
    h1_s[tid] = fmaxf(a0+a1, 0.f);
  }
  __syncthreads();
  { // W2
    float a0 = 0.f, a1 = 0.f;
    for(int pk=s*64; pk<s*64+64; pk+=2){
      ushort4_t wa = *reinterpret_cast<const ushort4_t*>(W2p + ((size_t)pk*256 + c)*4);
      ushort4_t wb = *reinterpret_cast<const ushort4_t*>(W2p + ((size_t)(pk+1)*256 + c)*4);
      a0 += bf2f(wa.x)*h1_s[4*pk] + bf2f(wa.y)*h1_s[4*pk+1]
          + bf2f(wa.z)*h1_s[4*pk+2] + bf2f(wa.w)*h1_s[4*pk+3];
      a1 += bf2f(wb.x)*h1_s[4*pk+4] + bf2f(wb.y)*h1_s[4*pk+5]
          + bf2f(wb.z)*h1_s[4*pk+6] + bf2f(wb.w)*h1_s[4*pk+7];
    }
    red_a[tid] = a0+a1;
  }
  __syncthreads();
  if (tid < 256){
    float rn = nw_s[tid] + (red_a[tid]+red_a[256+tid]+red_a[512+tid]+red_a[768+tid]) + b2[tid];
    nw_s[tid] = rn;
    if (split==0) rep_out[b*256+tid] = rn;
  }
  __syncthreads();
  { // slot LN
    float v = nw_s[c];
    float mu = blkSum16(v, s16)*(1.0f/1024.0f);
    float df = v - mu;
    float var = blkSum16(df*df, s16)*(1.0f/1024.0f);
    float rs = rsqrtf(var+1e-5f);
    if (s==0) ln_s[c] = df*rs*ln_sg[c]+ln_sb[c];
  }
  __syncthreads();
  { // q
    float a0 = 0.f, a1 = 0.f;
    for(int pk=s*16; pk<s*16+16; pk+=2){
      ushort4_t wa = *reinterpret_cast<const ushort4_t*>(Wqp + ((size_t)pk*256 + c)*4);
      ushort4_t wb = *reinterpret_cast<const ushort4_t*>(Wqp + ((size_t)(pk+1)*256 + c)*4);
      a0 += bf2f(wa.x)*ln_s[4*pk] + bf2f(wa.y)*ln_s[4*pk+1]
          + bf2f(wa.z)*ln_s[4*pk+2] + bf2f(wa.w)*ln_s[4*pk+3];
      a1 += bf2f(wb.x)*ln_s[4*pk+4] + bf2f(wb.y)*ln_s[4*pk+5]
          + bf2f(wb.z)*ln_s[4*pk+6] + bf2f(wb.w)*ln_s[4*pk+7];
    }
    red_a[tid] = a0+a1;
  }
  __syncthreads();
  if (tid < 256) q_s[tid] = red_a[tid]+red_a[256+tid]+red_a[512+tid]+red_a[768+tid];
  __syncthreads();
  { // p
    int h = tid>>8;
    float a0 = 0.f, a1 = 0.f;
    for(int pd=0;pd<16;pd+=2){
      ushort4_t wa = *reinterpret_cast<const ushort4_t*>(Wkp + ((size_t)pd*1024 + tid)*4);
      ushort4_t wb = *reinterpret_cast<const ushort4_t*>(Wkp + ((size_t)(pd+1)*1024 + tid)*4);
      a0 += bf2f(wa.x)*q_s[h*64+4*pd] + bf2f(wa.y)*q_s[h*64+4*pd+1]
          + bf2f(wa.z)*q_s[h*64+4*pd+2] + bf2f(wa.w)*q_s[h*64+4*pd+3];
      a1 += bf2f(wb.x)*q_s[h*64+4*pd+4] + bf2f(wb.y)*q_s[h*64+4*pd+5]
          + bf2f(wb.z)*q_s[h*64+4*pd+6] + bf2f(wb.w)*q_s[h*64+4*pd+7];
    }
    p_s[tid] = 2.0f*(a0+a1);
  }
  __syncthreads();
  // ---- phase A (unroll-2 rows, DPP reductions, depth-1 prefetch) ----
  int wid = tid>>6, lane = tid&63;
  int grp = tid>>5, cl = tid&31;
  f32x2 pp2[4][4];
  #pragma unroll
  for(int h=0;h<4;h++)
    #pragma unroll
    for(int j2=0;j2<4;j2++){
      pp2[h][j2].x = p_s[h*256 + cl*8 + j2*2];
      pp2[h][j2].y = p_s[h*256 + cl*8 + j2*2 + 1];
    }
  f32x2 u2[4][4] = {};
  float wsum[4] = {0,0,0,0};
  const unsigned short* xb = x + ((size_t)b*N_ + split*ROWS)*256;
  uint4 xa = *reinterpret_cast<const uint4*>(xb + (size_t)grp*256 + cl*8);
  uint4 xc = *reinterpret_cast<const uint4*>(xb + (size_t)(grp+32)*256 + cl*8);
  for(int it=0; it<NIT; ++it){
    int r0 = it*64 + grp, r1 = r0 + 32;
    uint4 nxa, nxc;
    if (it+1 < NIT){
      int p0 = (it+1)*64 + grp;
      nxa = *reinterpret_cast<const uint4*>(xb + (size_t)p0*256 + cl*8);
      nxc = *reinterpret_cast<const uint4*>(xb + (size_t)(p0+32)*256 + cl*8);
    }
    f32x2 x0[4], x1[4];
    x0[0]=up2(xa.x); x0[1]=up2(xa.y); x0[2]=up2(xa.z); x0[3]=up2(xa.w);
    x1[0]=up2(xc.x); x1[1]=up2(xc.y); x1[2]=up2(xc.z); x1[3]=up2(xc.w);
    float w0[4], w1[4];
    #pragma unroll
    for(int h=0;h<4;h++){
      f32x2 da = x0[0]*pp2[h][0] + x0[2]*pp2[h][2];
      f32x2 db = x0[1]*pp2[h][1] + x0[3]*pp2[h][3];
      da += db;
      float d0 = da.x + da.y;
      f32x2 ea = x1[0]*pp2[h][0] + x1[2]*pp2[h][2];
      f32x2 eb = x1[1]*pp2[h][1] + x1[3]*pp2[h][3];
      ea += eb;
      float d1 = ea.x + ea.y;
      d0 = rsum32(d0);
      d1 = rsum32(d1);
      w0[h] = sigm(d0) + 1e-8f;
      w1[h] = sigm(d1) + 1e-8f;
      wsum[h] += w0[h] + w1[h];
    }
    #pragma unroll
    for(int h=0;h<4;h++){
      f32x2 wa; wa.x = w0[h]; wa.y = w0[h];
      f32x2 wb; wb.x = w1[h]; wb.y = w1[h];
      #pragma unroll
      for(int j2=0;j2<4;j2++){ u2[h][j2] += wa*x0[j2]; u2[h][j2] += wb*x1[j2]; }
    }
    if (write_w && cl==0){
      float4 wv; wv.x=w0[0]; wv.y=w0[1]; wv.z=w0[2]; wv.w=w0[3];
      *reinterpret_cast<float4*>(w_buf + ((size_t)b*N_ + split*ROWS + r0)*4) = wv;
      float4 wz; wz.x=w1[0]; wz.y=w1[1]; wz.z=w1[2]; wz.w=w1[3];
      *reinterpret_cast<float4*>(w_buf + ((size_t)b*N_ + split*ROWS + r1)*4) = wz;
    }
    xa = nxa; xc = nxc;
  }
  #pragma unroll
  for(int h=0;h<4;h++){
    #pragma unroll
    for(int j2=0;j2<4;j2++){
      u2[h][j2].x += __shfl_xor(u2[h][j2].x,32);
      u2[h][j2].y += __shfl_xor(u2[h][j2].y,32);
    }
    wsum[h] += __shfl_xor(wsum[h],32);
  }
  __syncthreads();
  if (wid < 8 && lane < 32){
    #pragma unroll
    for(int h=0;h<4;h++){
      float4 a; a.x=u2[h][0].x; a.y=u2[h][0].y; a.z=u2[h][1].x; a.w=u2[h][1].y;
      float4 cc; cc.x=u2[h][2].x; cc.y=u2[h][2].y; cc.z=u2[h][3].x; cc.w=u2[h][3].y;
      *reinterpret_cast<float4*>(&u_red[wid][h*256 + cl*8    ]) = a;
      *reinterpret_cast<float4*>(&u_red[wid][h*256 + cl*8 + 4]) = cc;
    }
  }
  if (lane==0){
    #pragma unroll
    for(int h=0;h<4;h++) ws_red[wid][h] = wsum[h];
  }
  __syncthreads();
  if (wid >= 8 && lane < 32){
    #pragma unroll
    for(int h=0;h<4;h++){
      float4 a = *reinterpret_cast<const float4*>(&u_red[wid-8][h*256 + cl*8]);
      float4 cc = *reinterpret_cast<const float4*>(&u_red[wid-8][h*256 + cl*8 + 4]);
      a.x+=u2[h][0].x; a.y+=u2[h][0].y; a.z+=u2[h][1].x; a.w+=u2[h][1].y;
      cc.x+=u2[h][2].x; cc.y+=u2[h][2].y; cc.z+=u2[h][3].x; cc.w+=u2[h][3].y;
      *reinterpret_cast<float4*>(&u_red[wid-8][h*256 + cl*8    ]) = a;
      *reinterpret_cast<float4*>(&u_red[wid-8][h*256 + cl*8 + 4]) = cc;
    }
  }
  __syncthreads();
  {
    float sm = 0.f;
    #pragma unroll
    for(int w=0;w<8;w++) sm += u_red[w][tid];
    u_out[((size_t)split*128 + b)*1024 + tid] = sm;
  }
  if (tid < 4){
    float sm = 0.f;
    #pragma unroll
    for(int w=0;w<16;w++) sm += ws_red[w][tid];
    ws_out[((size_t)split*128 + b)*4 + tid] = sm;
  }
}

// ---------------- final step ----------------------------------------------
__global__ __launch_bounds__(1024) void k_finstep(
    const float* __restrict__ u_in, const float* __restrict__ ws_in,
    const float* __restrict__ rep_in,
    const unsigned short* __restrict__ Wvp, const unsigned short* __restrict__ Wip,
    const unsigned short* __restrict__ Whp, const float* __restrict__ bih,
    const float* __restrict__ bhh, const float* __restrict__ ln_rg,
    const float* __restrict__ ln_rb, const unsigned short* __restrict__ W1p,
    const unsigned short* __restrict__ W2p, const float* __restrict__ b2,
    float* __restrict__ out_rep, float* __restrict__ wsum_tot, int nsp_in){
  __shared__ float u_s[1024];
  __shared__ float att_s[256], rep_s[256], ln_s[256], nw_s[256];
  __shared__ float gi_s[768], gh_s[768];
  __shared__ float h1_s[1024], red_a[1024];
  __shared__ float ws_s[4]; __shared__ float s16[16];
  int b = blockIdx.x;
  int tid = threadIdx.x;
  int c = tid & 255, s = tid >> 8;
  {
    float acc = 0.f;
    for(int sp=0; sp<nsp_in; ++sp)
      acc += u_in[((size_t)sp*128 + b)*1024 + tid];
    u_s[tid] = acc;
    if (tid < 4){
      float w = 0.f;
      for(int sp=0; sp<nsp_in; ++sp) w += ws_in[((size_t)sp*128 + b)*4 + tid];
      ws_s[tid] = w; wsum_tot[b*4 + tid] = w;
    }
    if (tid < 256) rep_s[tid] = rep_in[b*256 + tid];
  }
  __syncthreads();
  {
    const float* uh = u_s + (c>>6)*256;
    float a0 = 0.f, a1 = 0.f;
    for(int pk=s*16; pk<s*16+16; pk+=2){
      ushort4_t wa = *reinterpret_cast<const ushort4_t*>(Wvp + ((size_t)pk*256 + c)*4);
      ushort4_t wb = *reinterpret_cast<const ushort4_t*>(Wvp + ((size_t)(pk+1)*256 + c)*4);
      a0 += bf2f(wa.x)*uh[4*pk] + bf2f(wa.y)*uh[4*pk+1]
          + bf2f(wa.z)*uh[4*pk+2] + bf2f(wa.w)*uh[4*pk+3];
      a1 += bf2f(wb.x)*uh[4*pk+4] + bf2f(wb.y)*uh[4*pk+5]
          + bf2f(wb.z)*uh[4*pk+6] + bf2f(wb.w)*uh[4*pk+7];
    }
    red_a[tid] = a0+a1;
  }
  __syncthreads();
  if (tid < 256) att_s[tid] = (red_a[tid]+red_a[256+tid]+red_a[512+tid]+red_a[768+tid]) / ws_s[tid>>6];
  __syncthreads();
  if (tid < 768){
    float gi0=0.f, gi1=0.f, gh0=0.f, gh1=0.f;
    for(int pk=0;pk<64;pk+=2){
      ushort4_t wi0 = *reinterpret_cast<const ushort4_t*>(Wip + ((size_t)pk*768 + tid)*4);
      ushort4_t wh0 = *reinterpret_cast<const ushort4_t*>(Whp + ((size_t)pk*768 + tid)*4);
      ushort4_t wi1 = *reinterpret_cast<const ushort4_t*>(Wip + ((size_t)(pk+1)*768 + tid)*4);
      ushort4_t wh1 = *reinterpret_cast<const ushort4_t*>(Whp + ((size_t)(pk+1)*768 + tid)*4);
      gi0 += bf2f(wi0.x)*att_s[4*pk] + bf2f(wi0.y)*att_s[4*pk+1]
           + bf2f(wi0.z)*att_s[4*pk+2] + bf2f(wi0.w)*att_s[4*pk+3];
      gh0 += bf2f(wh0.x)*rep_s[4*pk] + bf2f(wh0.y)*rep_s[4*pk+1]
           + bf2f(wh0.z)*rep_s[4*pk+2] + bf2f(wh0.w)*rep_s[4*pk+3];
      gi1 += bf2f(wi1.x)*att_s[4*pk+4] + bf2f(wi1.y)*att_s[4*pk+5]
           + bf2f(wi1.z)*att_s[4*pk+6] + bf2f(wi1.w)*att_s[4*pk+7];
      gh1 += bf2f(wh1.x)*rep_s[4*pk+4] + bf2f(wh1.y)*rep_s[4*pk+5]
           + bf2f(wh1.z)*rep_s[4*pk+6] + bf2f(wh1.w)*rep_s[4*pk+7];
    }
    gi_s[tid] = gi0+gi1 + bih[tid];
    gh_s[tid] = gh0+gh1 + bhh[tid];
  }
  __syncthreads();
  if (tid < 256){
    float rr = sigm(gi_s[tid]     + gh_s[tid]);
    float zz = sigm(gi_s[256+tid] + gh_s[256+tid]);
    float t3 = tanhf(gi_s[512+tid] + rr*gh_s[512+tid]);
    nw_s[tid] = (1.f-zz)*t3 + zz*rep_s[tid];
  }
  __syncthreads();
  {
    float v = nw_s[c];
    float mu = blkSum16(v, s16)*(1.0f/1024.0f);
    float df = v - mu;
    float var = blkSum16(df*df, s16)*(1.0f/1024.0f);
    float rs = rsqrtf(var+1e-5f);
    if (s==0) ln_s[c] = df*rs*ln_rg[c]+ln_rb[c];
  }
  __syncthreads();
  {
    float a0 = 0.f, a1 = 0.f;
    for(int pk=0;pk<64;pk+=2){
      ushort4_t wa = *reinterpret_cast<const ushort4_t*>(W1p + ((size_t)pk*1024 + tid)*4);
      ushort4_t wb = *reinterpret_cast<const ushort4_t*>(W1p + ((size_t)(pk+1)*1024 + tid)*4);
      a0 += bf2f(wa.x)*ln_s[4*pk] + bf2f(wa.y)*ln_s[4*pk+1]
          + bf2f(wa.z)*ln_s[4*pk+2] + bf2f(wa.w)*ln_s[4*pk+3];
      a1 += bf2f(wb.x)*ln_s[4*pk+4] + bf2f(wb.y)*ln_s[4*pk+5]
          + bf2f(wb.z)*ln_s[4*pk+6] + bf2f(wb.w)*ln_s[4*pk+7];
    }
    h1_s[tid] = fmaxf(a0+a1, 0.f);
  }
  __syncthreads();
  {
    float a0 = 0.f, a1 = 0.f;
    for(int pk=s*64; pk<s*64+64; pk+=2){
      ushort4_t wa = *reinterpret_cast<const ushort4_t*>(W2p + ((size_t)pk*256 + c)*4);
      ushort4_t wb = *reinterpret_cast<const ushort4_t*>(W2p + ((size_t)(pk+1)*256 + c)*4);
      a0 += bf2f(wa.x)*h1_s[4*pk] + bf2f(wa.y)*h1_s[4*pk+1]
          + bf2f(wa.z)*h1_s[4*pk+2] + bf2f(wa.w)*h1_s[4*pk+3];
      a1 += bf2f(wb.x)*h1_s[4*pk+4] + bf2f(wb.y)*h1_s[4*pk+5]
          + bf2f(wb.z)*h1_s[4*pk+6] + bf2f(wb.w)*h1_s[4*pk+7];
    }
    red_a[tid] = a0+a1;
  }
  __syncthreads();
  if (tid < 256){
    float rn = nw_s[tid] + (red_a[tid]+red_a[256+tid]+red_a[512+tid]+red_a[768+tid]) + b2[tid];
    out_rep[b*256+tid] = rn;
  }
}

// ---------------- final w output ------------------------------------------
__global__ __launch_bounds__(256) void k_wout(
    const float* __restrict__ w_buf, const float* __restrict__ wsum_tot,
    float* __restrict__ out){
  int idx = blockIdx.x*256 + threadIdx.x;     // 0..524287
  int b = idx>>12;
  float4 w4 = *reinterpret_cast<const float4*>(w_buf + (size_t)idx*4);
  out[idx] = w4.x/wsum_tot[b*4+0] + w4.y/wsum_tot[b*4+1]
           + w4.z/wsum_tot[b*4+2] + w4.w/wsum_tot[b*4+3];
}

extern "C" void kernel_launch(void* const* d_in, const int* in_sizes, int n_in,
                              void* d_out, int out_size, void* d_ws, size_t ws_size,
                              hipStream_t stream){
  const float* inputs  = (const float*)d_in[0];
  const float* eps     = (const float*)d_in[1];
  const float* init_mu = (const float*)d_in[2];
  const float* init_lv = (const float*)d_in[3];
  const float* Wk      = (const float*)d_in[4];
  const float* Wv      = (const float*)d_in[5];
  const float* Wq      = (const float*)d_in[6];
  const float* ln_in_g = (const float*)d_in[7];
  const float* ln_in_b = (const float*)d_in[8];
  const float* ln_sg   = (const float*)d_in[9];
  const float* ln_sb   = (const float*)d_in[10];
  const float* ln_rg   = (const float*)d_in[11];
  const float* ln_rb   = (const float*)d_in[12];
  const float* Wih     = (const float*)d_in[13];
  const float* Whh     = (const float*)d_in[14];
  const float* bih     = (const float*)d_in[15];
  const float* bhh     = (const float*)d_in[16];
  const float* W1      = (const float*)d_in[17];
  const float* W2      = (const float*)d_in[18];
  const float* b2      = (const float*)d_in[19];

  char* ws = (char*)d_ws;
  size_t off = 0;
  auto alloc = [&](size_t bytes)->void*{
    void* p = ws + off; off += (bytes + 255) & ~(size_t)255; return p;
  };
  unsigned short* x   = (unsigned short*)alloc((size_t)128*N_*256*2);
  unsigned short* Wvp = (unsigned short*)alloc(65536*2);
  unsigned short* Wip = (unsigned short*)alloc(196608*2);
  unsigned short* Whp = (unsigned short*)alloc(196608*2);
  unsigned short* W1p = (unsigned short*)alloc(262144*2);
  unsigned short* W2p = (unsigned short*)alloc(262144*2);
  unsigned short* Wqp = (unsigned short*)alloc(65536*2);
  unsigned short* Wkp = (unsigned short*)alloc(65536*2);
  float* p0    = (float*)alloc((size_t)128*1024*4);
  float* uA    = (float*)alloc((size_t)NSPL1*128*1024*4);
  float* uB    = (float*)alloc((size_t)NSPL1*128*1024*4);
  float* wsA   = (float*)alloc(NSPL1*128*4*4);
  float* wsB   = (float*)alloc(NSPL1*128*4*4);
  float* repA  = (float*)alloc(128*256*4);
  float* repB  = (float*)alloc(128*256*4);
  float* wsum_tot = (float*)alloc(512*4);
  float* w_buf = (float*)alloc((size_t)128*N_*4*4);

  float* out_rep = (float*)d_out;
  float* out_w   = out_rep + 128*256;

  k_prep<<<1024,256,0,stream>>>(Wv,Wih,Whh,W1,W2,Wq,Wk, Wvp,Wip,Whp,W1p,W2p,Wqp,Wkp);
  k_init<<<128,256,0,stream>>>(eps, init_mu, init_lv, ln_sg, ln_sb, Wq, Wkp, repA, p0);
  k_lnattn<<<dim3(NSPL1,128),1024,0,stream>>>(inputs, ln_in_g, ln_in_b, p0, x, uA, wsA);
  k_attnstep<<<dim3(NSPL2,128),1024,0,stream>>>(x, uA, wsA, repA, repB,
      Wvp,Wip,Whp,bih,bhh,ln_rg,ln_rb,W1p,W2p,b2,ln_sg,ln_sb,Wqp,Wkp,
      uB, wsB, w_buf, 0, NSPL1);
  k_attnstep<<<dim3(NSPL2,128),1024,0,stream>>>(x, uB, wsB, repB, repA,
      Wvp,Wip,Whp,bih,bhh,ln_rg,ln_rb,W1p,W2p,b2,ln_sg,ln_sb,Wqp,Wkp,
      uA, wsA, w_buf, 0, NSPL2);
  k_attnstep<<<dim3(NSPL2,128),1024,0,stream>>>(x, uA, wsA, repA, repB,
      Wvp,Wip,Whp,bih,bhh,ln_rg,ln_rb,W1p,W2p,b2,ln_sg,ln_sb,Wqp,Wkp,
      uB, wsB, w_buf, 1, NSPL2);
  k_finstep<<<128,1024,0,stream>>>(uB, wsB, repB,
      Wvp,Wip,Whp,bih,bhh,ln_rg,ln_rb,W1p,W2p,b2, out_rep, wsum_tot, NSPL2);
  k_wout<<<2048,256,0,stream>>>(w_buf, wsum_tot, out_w);
}